// Round 6
// baseline (923.449 us; speedup 1.0000x reference)
//
#include <hip/hip_runtime.h>
#include <hip/hip_bf16.h>
#include <stdint.h>

#define B_ 4
#define S_IN 32768
#define C1V 128
#define L1V 16384
#define C2V 256
#define L2V 8192
#define C3V 512
#define L3V 4096
#define VOCABV 2048
#define KCB 4

typedef _Float16 half8 __attribute__((ext_vector_type(8)));
typedef float floatx4 __attribute__((ext_vector_type(4)));
typedef float floatx16 __attribute__((ext_vector_type(16)));

#define AS1 __attribute__((address_space(1)))
#define AS3 __attribute__((address_space(3)))

__device__ __forceinline__ void gload_lds16(const void* g, void* l) {
    __builtin_amdgcn_global_load_lds((const AS1 void*)g, (AS3 void*)l, 16, 0, 0);
}

// read 8 halfs at a 4B-aligned LDS address (4x ds_read_b32)
__device__ __forceinline__ half8 lds_read_half8_a4(const _Float16* p) {
    union { uint32_t u[4]; half8 h; } t;
    const uint32_t* w = (const uint32_t*)p;
    t.u[0] = w[0]; t.u[1] = w[1]; t.u[2] = w[2]; t.u[3] = w[3];
    return t.h;
}

// ---------------- conv1: [B,1,S] -> [B,128,16384], k=7 s=2 p=3, relu ----------------
__global__ void conv1_kernel(const float* __restrict__ x, const float* __restrict__ w,
                             const float* __restrict__ bias, float* __restrict__ out) {
    __shared__ float xs[2 * 256 + 6];
    __shared__ float ws[7];
    const int l0 = blockIdx.x * 256;
    const int co = blockIdx.y;
    const int b  = blockIdx.z;
    const int tid = threadIdx.x;
    const float* xb = x + (size_t)b * S_IN;
    for (int n = tid; n < 2 * 256 + 6; n += 256) {
        int p = 2 * l0 - 3 + n;
        xs[n] = (p >= 0 && p < S_IN) ? xb[p] : 0.f;
    }
    if (tid < 7) ws[tid] = w[co * 7 + tid];
    __syncthreads();
    float acc = bias[co];
    const int base = 2 * tid;
#pragma unroll
    for (int t = 0; t < 7; ++t) acc = fmaf(ws[t], xs[base + t], acc);
    acc = fmaxf(acc, 0.f);
    out[((size_t)(b * C1V + co)) * L1V + l0 + tid] = acc;
}

// ---------------- weight prep: w[co][ci][7] fp32 -> hi/lo f16 planes [co][ci*8+u] ----
__global__ void wsplit_kernel(const float* __restrict__ w, _Float16* __restrict__ wh,
                              _Float16* __restrict__ wl, int cin, int cout) {
    int idx = blockIdx.x * 256 + threadIdx.x;
    if (idx >= cin * cout) return;
    int co = idx / cin;
    int ci = idx - co * cin;
    const float* src = w + ((size_t)co * cin + ci) * 7;
    half8 h, l;
    h[0] = (_Float16)0.f; l[0] = (_Float16)0.f;
#pragma unroll
    for (int u = 1; u < 8; ++u) {
        float v = src[u - 1] * 1024.f;
        _Float16 hh = (_Float16)v;
        h[u] = hh;
        l[u] = (_Float16)(v - (float)hh);
    }
    size_t o = (size_t)co * (cin * 8) + ci * 8;
    *(half8*)(wh + o) = h;
    *(half8*)(wl + o) = l;
}

// ---------------- conv2 via f16 3-product MFMA: A=W (m=co), B=X windows (n=l) -------
__global__ __launch_bounds__(256, 2) void conv2_mfma_kernel(
    const float* __restrict__ in, const _Float16* __restrict__ WH,
    const _Float16* __restrict__ WL, const float* __restrict__ bias,
    float* __restrict__ out) {
    __shared__ _Float16 XsH[4 * 272], XsL[4 * 272];
    __shared__ _Float16 WsH[128 * 32], WsL[128 * 32];
    const int tid = threadIdx.x;
    const int wave = tid >> 6;
    const int lane = tid & 63;
    const int wm = wave >> 1, wn = wave & 1;
    const int q  = lane >> 4;
    const int cl = lane & 15;
    const int l0  = blockIdx.x * 128;
    const int co0 = blockIdx.y * 128;
    const int b   = blockIdx.z;
    const float* inb = in + (size_t)b * C1V * L1V;

    floatx4 acc[4][4];
#pragma unroll
    for (int a = 0; a < 4; ++a)
#pragma unroll
        for (int n = 0; n < 4; ++n) acc[a][n] = (floatx4){0.f, 0.f, 0.f, 0.f};

    for (int ch = 0; ch < 32; ++ch) {
        __syncthreads();
        for (int n = tid; n < 4 * 264; n += 256) {
            int ci = n / 264;
            int m  = n - ci * 264;
            int p  = 2 * l0 - 4 + m;
            float v = (p >= 0 && p < L1V) ? inb[(size_t)(ch * 4 + ci) * L1V + p] * 1024.f : 0.f;
            _Float16 h = (_Float16)v;
            XsH[ci * 272 + m] = h;
            XsL[ci * 272 + m] = (_Float16)(v - (float)h);
        }
        const int k0 = ch * 32;
        for (int g = wave; g < 8; g += 4) {
            const _Float16* gh = WH + (size_t)(co0 + g * 16 + (lane >> 2)) * 1024 + k0 + (lane & 3) * 8;
            const _Float16* gl = WL + (size_t)(co0 + g * 16 + (lane >> 2)) * 1024 + k0 + (lane & 3) * 8;
            gload_lds16(gh, (char*)WsH + g * 1024);
            gload_lds16(gl, (char*)WsL + g * 1024);
        }
        asm volatile("s_waitcnt vmcnt(0)" ::: "memory");
        __syncthreads();

        half8 awh[4], awl[4], bxh[4], bxl[4];
#pragma unroll
        for (int a = 0; a < 4; ++a) {
            const int ro = (wm * 64 + a * 16 + cl) * 32 + q * 8;
            awh[a] = *(const half8*)&WsH[ro];
            awl[a] = *(const half8*)&WsL[ro];
        }
#pragma unroll
        for (int n = 0; n < 4; ++n) {
            const int lrel = wn * 64 + n * 16 + cl;
            bxh[n] = lds_read_half8_a4(&XsH[q * 272 + 2 * lrel]);
            bxl[n] = lds_read_half8_a4(&XsL[q * 272 + 2 * lrel]);
        }
#pragma unroll
        for (int a = 0; a < 4; ++a)
#pragma unroll
            for (int n = 0; n < 4; ++n) {
                acc[a][n] = __builtin_amdgcn_mfma_f32_16x16x32_f16(awh[a], bxh[n], acc[a][n], 0, 0, 0);
                acc[a][n] = __builtin_amdgcn_mfma_f32_16x16x32_f16(awl[a], bxh[n], acc[a][n], 0, 0, 0);
                acc[a][n] = __builtin_amdgcn_mfma_f32_16x16x32_f16(awh[a], bxl[n], acc[a][n], 0, 0, 0);
            }
    }

    float bv[4][4];
#pragma unroll
    for (int a = 0; a < 4; ++a)
#pragma unroll
        for (int r = 0; r < 4; ++r) bv[a][r] = bias[co0 + wm * 64 + a * 16 + q * 4 + r];
#pragma unroll
    for (int a = 0; a < 4; ++a)
#pragma unroll
        for (int n = 0; n < 4; ++n) {
            const int l = l0 + wn * 64 + n * 16 + cl;
#pragma unroll
            for (int r = 0; r < 4; ++r) {
                const int co = co0 + wm * 64 + a * 16 + q * 4 + r;
                float vv = fmaxf(acc[a][n][r] * (1.f / 1048576.f) + bv[a][r], 0.f);
                out[((size_t)(b * C2V + co)) * L2V + l] = vv;
            }
        }
}

// ---------------- conv3 via f16 3-product MFMA: A=X windows (m=l), B=W (n=co) -------
__global__ __launch_bounds__(256, 2) void conv3_mfma_kernel(
    const float* __restrict__ in, const _Float16* __restrict__ WH,
    const _Float16* __restrict__ WL, const float* __restrict__ bias,
    _Float16* __restrict__ outh) {
    __shared__ _Float16 XsH[4 * 272], XsL[4 * 272];
    __shared__ _Float16 WsH[128 * 32], WsL[128 * 32];
    const int tid = threadIdx.x;
    const int wave = tid >> 6;
    const int lane = tid & 63;
    const int wm = wave >> 1, wn = wave & 1;
    const int q  = lane >> 4;
    const int cl = lane & 15;
    const int l0  = blockIdx.x * 128;
    const int co0 = blockIdx.y * 128;
    const int b   = blockIdx.z;
    const float* inb = in + (size_t)b * C2V * L2V;

    floatx4 acc[4][4];
#pragma unroll
    for (int a = 0; a < 4; ++a)
#pragma unroll
        for (int n = 0; n < 4; ++n) acc[a][n] = (floatx4){0.f, 0.f, 0.f, 0.f};

    for (int ch = 0; ch < 64; ++ch) {
        __syncthreads();
        for (int n = tid; n < 4 * 264; n += 256) {
            int ci = n / 264;
            int m  = n - ci * 264;
            int p  = 2 * l0 - 4 + m;
            float v = (p >= 0 && p < L2V) ? inb[(size_t)(ch * 4 + ci) * L2V + p] * 1024.f : 0.f;
            _Float16 h = (_Float16)v;
            XsH[ci * 272 + m] = h;
            XsL[ci * 272 + m] = (_Float16)(v - (float)h);
        }
        const int k0 = ch * 32;
        for (int g = wave; g < 8; g += 4) {
            const _Float16* gh = WH + (size_t)(co0 + g * 16 + (lane >> 2)) * 2048 + k0 + (lane & 3) * 8;
            const _Float16* gl = WL + (size_t)(co0 + g * 16 + (lane >> 2)) * 2048 + k0 + (lane & 3) * 8;
            gload_lds16(gh, (char*)WsH + g * 1024);
            gload_lds16(gl, (char*)WsL + g * 1024);
        }
        asm volatile("s_waitcnt vmcnt(0)" ::: "memory");
        __syncthreads();

        half8 axh[4], axl[4], bwh[4], bwl[4];
#pragma unroll
        for (int a = 0; a < 4; ++a) {
            const int lrel = wm * 64 + a * 16 + cl;
            axh[a] = lds_read_half8_a4(&XsH[q * 272 + 2 * lrel]);
            axl[a] = lds_read_half8_a4(&XsL[q * 272 + 2 * lrel]);
        }
#pragma unroll
        for (int n = 0; n < 4; ++n) {
            const int ro = (wn * 64 + n * 16 + cl) * 32 + q * 8;
            bwh[n] = *(const half8*)&WsH[ro];
            bwl[n] = *(const half8*)&WsL[ro];
        }
#pragma unroll
        for (int a = 0; a < 4; ++a)
#pragma unroll
            for (int n = 0; n < 4; ++n) {
                acc[a][n] = __builtin_amdgcn_mfma_f32_16x16x32_f16(axh[a], bwh[n], acc[a][n], 0, 0, 0);
                acc[a][n] = __builtin_amdgcn_mfma_f32_16x16x32_f16(axl[a], bwh[n], acc[a][n], 0, 0, 0);
                acc[a][n] = __builtin_amdgcn_mfma_f32_16x16x32_f16(axh[a], bwl[n], acc[a][n], 0, 0, 0);
            }
    }

    float bv[4];
#pragma unroll
    for (int n = 0; n < 4; ++n) bv[n] = bias[co0 + wn * 64 + n * 16 + cl];
#pragma unroll
    for (int a = 0; a < 4; ++a)
#pragma unroll
        for (int n = 0; n < 4; ++n) {
            const int co = co0 + wn * 64 + n * 16 + cl;
#pragma unroll
            for (int r = 0; r < 4; ++r) {
                const int l = l0 + wm * 64 + a * 16 + q * 4 + r;
                float f = acc[a][n][r] * (1.f / 1048576.f) + bv[n];
                float s = f * 1024.f;
                _Float16 h = (_Float16)s;
                _Float16 lo = (_Float16)(s - (float)h);
                _Float16* dst = outh + ((size_t)b * L3V + l) * 1024 + co;
                dst[0] = h;
                dst[512] = lo;
            }
        }
}

// ---------------- fused codebook prep: rowsq*2^19 + x1024 hi/lo f16 split ----------
__global__ void cbprep_kernel(const float* __restrict__ cb, _Float16* __restrict__ y,
                              float* __restrict__ c2p) {
    const int r = blockIdx.x;
    const int lane = threadIdx.x;  // 64
    const float* row = cb + (size_t)r * 512;
    float4 a = *(const float4*)&row[lane * 8];
    float4 c = *(const float4*)&row[lane * 8 + 4];
    float s = a.x * a.x + a.y * a.y + a.z * a.z + a.w * a.w
            + c.x * c.x + c.y * c.y + c.z * c.z + c.w * c.w;
#pragma unroll
    for (int off = 32; off > 0; off >>= 1) s += __shfl_down(s, off, 64);
    if (lane == 0) c2p[r] = s * 524288.f;  // 2^19

    const float e[8] = {a.x, a.y, a.z, a.w, c.x, c.y, c.z, c.w};
    half8 hv, lv;
#pragma unroll
    for (int i = 0; i < 8; ++i) {
        float v = e[i] * 1024.f;
        _Float16 h = (_Float16)v;
        hv[i] = h;
        lv[i] = (_Float16)(v - (float)h);
    }
    *(half8*)(y + (size_t)r * 1024 + lane * 8) = hv;
    *(half8*)(y + (size_t)r * 1024 + 512 + lane * 8) = lv;
}

// ---------------- MFMA cross-GEMM + fused argmin, 32x32x16 shape -------------------
// Block tile 128l x 256v, wave tile 64l x 128v = 2x4 MFMA tiles of 32x32 (acc 8x16f).
// acc = Ahi*Bhi + Alo*Bhi + Ahi*Blo = 2^20*cross; key = acc - c2*2^19 (argmax).
// A/B frag: m=lane&31, k=(lane>>5)*8+j. C/D: col=lane&31, row=(reg&3)+8*(reg>>2)+4*(lane>>5).
__global__ __launch_bounds__(256, 2) void cross_mfma_kernel(
    const _Float16* __restrict__ Af, const _Float16* __restrict__ Bf,
    const float* __restrict__ c2p,
    int* __restrict__ tok_i, float* __restrict__ tok_f) {

    __shared__ _Float16 AsH[128 * 32], AsL[128 * 32];   // 8 KB each
    __shared__ _Float16 BsH[256 * 32], BsL[256 * 32];   // 16 KB each
    __shared__ float slotv[2][128];
    __shared__ int   sloti[2][128];

    const int tid  = threadIdx.x;
    const int wave = tid >> 6;
    const int lane = tid & 63;
    const int wm = wave >> 1, wn = wave & 1;
    const int m32 = lane & 31;     // row/col within 32-tile
    const int kh  = lane >> 5;     // k-half selector (0..1)

    const int l0 = blockIdx.x * 128;
    const int k  = blockIdx.y;
    const int b  = blockIdx.z;

    const _Float16* Ab = Af + (size_t)(b * L3V + l0) * 1024;
    const _Float16* Bb = Bf + (size_t)k * VOCABV * 1024;

    if (tid < 128) {
        slotv[0][tid] = -3.4e38f; slotv[1][tid] = -3.4e38f;
        sloti[0][tid] = 0;        sloti[1][tid] = 0;
    }

    const int rsub = tid >> 2;       // 0..63: row within 64-row staging group
    const int seg  = tid & 3;        // 16B segment within 64B row

#pragma unroll 1
    for (int vt = 0; vt < 8; ++vt) {
        const _Float16* Bt = Bb + (size_t)(vt * 256) * 1024;
        floatx16 acc[2][4];
#pragma unroll
        for (int mt = 0; mt < 2; ++mt)
#pragma unroll
            for (int nt = 0; nt < 4; ++nt) acc[mt][nt] = (floatx16)(0.f);

#pragma unroll 1
        for (int ko = 0; ko < 512; ko += 32) {
            __syncthreads();
#pragma unroll
            for (int i = 0; i < 2; ++i) {
                const _Float16* ga = Ab + (size_t)(i * 64 + rsub) * 1024 + ko + seg * 8;
                gload_lds16(ga,       (char*)AsH + i * 4096 + tid * 16);
                gload_lds16(ga + 512, (char*)AsL + i * 4096 + tid * 16);
            }
#pragma unroll
            for (int i = 0; i < 4; ++i) {
                const _Float16* gb = Bt + (size_t)(i * 64 + rsub) * 1024 + ko + seg * 8;
                gload_lds16(gb,       (char*)BsH + i * 4096 + tid * 16);
                gload_lds16(gb + 512, (char*)BsL + i * 4096 + tid * 16);
            }
            asm volatile("s_waitcnt vmcnt(0)" ::: "memory");
            __syncthreads();

            half8 ah[2][2], al[2][2];
#pragma unroll
            for (int mt = 0; mt < 2; ++mt)
#pragma unroll
                for (int kk = 0; kk < 2; ++kk) {
                    const int ro = (wm * 64 + mt * 32 + m32) * 32 + kk * 16 + kh * 8;
                    ah[mt][kk] = *(const half8*)&AsH[ro];
                    al[mt][kk] = *(const half8*)&AsL[ro];
                }
#pragma unroll
            for (int nt = 0; nt < 4; ++nt) {
                const int rb = (wn * 128 + nt * 32 + m32) * 32 + kh * 8;
                half8 bh0 = *(const half8*)&BsH[rb];
                half8 bl0 = *(const half8*)&BsL[rb];
                half8 bh1 = *(const half8*)&BsH[rb + 16];
                half8 bl1 = *(const half8*)&BsL[rb + 16];
#pragma unroll
                for (int mt = 0; mt < 2; ++mt) {
                    acc[mt][nt] = __builtin_amdgcn_mfma_f32_32x32x16_f16(ah[mt][0], bh0, acc[mt][nt], 0, 0, 0);
                    acc[mt][nt] = __builtin_amdgcn_mfma_f32_32x32x16_f16(al[mt][0], bh0, acc[mt][nt], 0, 0, 0);
                    acc[mt][nt] = __builtin_amdgcn_mfma_f32_32x32x16_f16(ah[mt][0], bl0, acc[mt][nt], 0, 0, 0);
                    acc[mt][nt] = __builtin_amdgcn_mfma_f32_32x32x16_f16(ah[mt][1], bh1, acc[mt][nt], 0, 0, 0);
                    acc[mt][nt] = __builtin_amdgcn_mfma_f32_32x32x16_f16(al[mt][1], bh1, acc[mt][nt], 0, 0, 0);
                    acc[mt][nt] = __builtin_amdgcn_mfma_f32_32x32x16_f16(ah[mt][1], bl1, acc[mt][nt], 0, 0, 0);
                }
            }
        }

        // per-vt argmax epilogue: key = acc - c2; v index = vt*256 + wn*128 + nt*32 + m32
        float c2v[4];
#pragma unroll
        for (int nt = 0; nt < 4; ++nt)
            c2v[nt] = c2p[k * VOCABV + vt * 256 + wn * 128 + nt * 32 + m32];
#pragma unroll
        for (int mt = 0; mt < 2; ++mt)
#pragma unroll
            for (int r = 0; r < 16; ++r) {
                float bv = acc[mt][0][r] - c2v[0];
                int   bi = vt * 256 + wn * 128 + m32;
#pragma unroll
                for (int nt = 1; nt < 4; ++nt) {
                    float m = acc[mt][nt][r] - c2v[nt];
                    int   vi = vt * 256 + wn * 128 + nt * 32 + m32;
                    if (m > bv) { bv = m; bi = vi; }
                }
#pragma unroll
                for (int msk = 1; msk < 32; msk <<= 1) {
                    float ov = __shfl_xor(bv, msk, 64);
                    int   oi = __shfl_xor(bi, msk, 64);
                    if (ov > bv || (ov == bv && oi < bi)) { bv = ov; bi = oi; }
                }
                if (m32 == 0) {
                    const int row = wm * 64 + mt * 32 + (r & 3) + 8 * (r >> 2) + 4 * kh;
                    float cur = slotv[wn][row];
                    int   ci  = sloti[wn][row];
                    if (bv > cur || (bv == cur && bi < ci)) {
                        slotv[wn][row] = bv;
                        sloti[wn][row] = bi;
                    }
                }
            }
    }

    __syncthreads();
    if (tid < 128) {
        float v0 = slotv[0][tid], v1 = slotv[1][tid];
        int   i0 = sloti[0][tid], i1 = sloti[1][tid];
        bool t1 = (v1 > v0);  // wn=1 indices always larger: ties keep wn=0
        int best = t1 ? i1 : i0;
        const int n = (b * KCB + k) * L3V + l0 + tid;
        tok_i[n] = best;
        tok_f[n] = (float)best;
    }
}

// ---------------- embedding mean over 4 codebooks ----------------
__global__ void emb_kernel(const int* __restrict__ tokens, const float* __restrict__ E,
                           float* __restrict__ out) {
    const int l = blockIdx.x;
    const int b = blockIdx.y;
    const int h4 = threadIdx.x * 4;
    const int t0 = tokens[((size_t)(b * KCB + 0)) * L3V + l];
    const int t1 = tokens[((size_t)(b * KCB + 1)) * L3V + l];
    const int t2 = tokens[((size_t)(b * KCB + 2)) * L3V + l];
    const int t3 = tokens[((size_t)(b * KCB + 3)) * L3V + l];
    const float4 e0 = *(const float4*)&E[(size_t)t0 * 512 + h4];
    const float4 e1 = *(const float4*)&E[(size_t)t1 * 512 + h4];
    const float4 e2 = *(const float4*)&E[(size_t)t2 * 512 + h4];
    const float4 e3 = *(const float4*)&E[(size_t)t3 * 512 + h4];
    float4 r;
    r.x = (e0.x + e1.x + e2.x + e3.x) * 0.25f;
    r.y = (e0.y + e1.y + e2.y + e3.y) * 0.25f;
    r.z = (e0.z + e1.z + e2.z + e3.z) * 0.25f;
    r.w = (e0.w + e1.w + e2.w + e3.w) * 0.25f;
    *(float4*)&out[((size_t)b * L3V + l) * 512 + h4] = r;
}

extern "C" void kernel_launch(void* const* d_in, const int* in_sizes, int n_in,
                              void* d_out, int out_size, void* d_ws, size_t ws_size,
                              hipStream_t stream) {
    const float* audio = (const float*)d_in[0];
    const float* w1 = (const float*)d_in[1];
    const float* b1 = (const float*)d_in[2];
    const float* w2 = (const float*)d_in[3];
    const float* b2 = (const float*)d_in[4];
    const float* w3 = (const float*)d_in[5];
    const float* b3 = (const float*)d_in[6];
    const float* cb = (const float*)d_in[7];
    const float* E  = (const float*)d_in[8];

    float* out_tok = (float*)d_out;
    float* out_emb = out_tok + (size_t)B_ * KCB * L3V;

    float* ws = (float*)d_ws;
    size_t off = 0;
    float* x1  = ws + off; off += (size_t)B_ * C1V * L1V;            // conv1 out, later Afh
    float* x2f = ws + off; off += (size_t)B_ * C2V * L2V / 2;        // conv2 out
    float* bfh_f = ws + off; off += (size_t)KCB * VOCABV * 1024 / 2; // Bfh
    float* w2h_f = ws + off; off += (size_t)C2V * (C1V * 8) / 2;
    float* w2l_f = ws + off; off += (size_t)C2V * (C1V * 8) / 2;
    float* w3h_f = ws + off; off += (size_t)C3V * (C2V * 8) / 2;
    float* w3l_f = ws + off; off += (size_t)C3V * (C2V * 8) / 2;
    float* c2p = ws + off; off += (size_t)KCB * VOCABV;
    int*   tok = (int*)(ws + off); off += (size_t)B_ * KCB * L3V;

    _Float16* Afh = (_Float16*)x1;   // conv3 writes over x1 (dead after conv2)
    _Float16* Bfh = (_Float16*)bfh_f;
    _Float16* W2H = (_Float16*)w2h_f; _Float16* W2L = (_Float16*)w2l_f;
    _Float16* W3H = (_Float16*)w3h_f; _Float16* W3L = (_Float16*)w3l_f;

    wsplit_kernel<<<(C2V * C1V + 255) / 256, 256, 0, stream>>>(w2, W2H, W2L, C1V, C2V);
    wsplit_kernel<<<(C3V * C2V + 255) / 256, 256, 0, stream>>>(w3, W3H, W3L, C2V, C3V);

    conv1_kernel<<<dim3(L1V / 256, C1V, B_), 256, 0, stream>>>(audio, w1, b1, x1);

    conv2_mfma_kernel<<<dim3(L2V / 128, C2V / 128, B_), 256, 0, stream>>>(
        x1, W2H, W2L, b2, x2f);

    conv3_mfma_kernel<<<dim3(L3V / 128, C3V / 128, B_), 256, 0, stream>>>(
        x2f, W3H, W3L, b3, Afh);

    cbprep_kernel<<<KCB * VOCABV, 64, 0, stream>>>(cb, Bfh, c2p);

    cross_mfma_kernel<<<dim3(L3V / 128, KCB, B_), 256, 0, stream>>>(
        Afh, Bfh, c2p, tok, out_tok);

    emb_kernel<<<dim3(L3V, B_), 128, 0, stream>>>(tok, E, out_emb);
}